// Round 1
// baseline (156.327 us; speedup 1.0000x reference)
//
#include <hip/hip_runtime.h>

typedef __attribute__((ext_vector_type(4))) float  f4;
typedef __attribute__((ext_vector_type(2))) float  f2;
typedef __attribute__((ext_vector_type(8))) short  short8;
typedef __attribute__((ext_vector_type(4))) float  f32x4;
typedef __attribute__((ext_vector_type(2))) unsigned int u32x2;

static __device__ __forceinline__ unsigned short f2bf(float f) {
    unsigned u = __builtin_bit_cast(unsigned, f);
    unsigned r = (u + 0x7FFFu + ((u >> 16) & 1u)) >> 16;   // RNE
    return (unsigned short)r;
}

// ---------------- K0: WhT[d][c] = bf16(gamma*Wh[c][d]); gb = gamma*bh ----------------
__global__ __launch_bounds__(256) void k_setup(const float* __restrict__ Wh,
                                               const float* __restrict__ bh,
                                               const float* __restrict__ gamma,
                                               unsigned short* __restrict__ WhT,
                                               float* __restrict__ gb) {
    const int c = blockIdx.x;      // 0..255
    const int d = threadIdx.x;     // 0..255
    const float g = gamma[0];
    WhT[d * 256 + c] = f2bf(g * Wh[c * 256 + d]);
    if (blockIdx.x == 0) gb[d] = g * bh[d];
}

// ---------------- KA: f,g (fp32) + partial s ----------------
// grid 256 x 512 threads. Each block: 4 pixel-groups of 4 pixels.
__global__ __launch_bounds__(512) void ka(const float* __restrict__ x,
                                          const float* __restrict__ Wf,
                                          const float* __restrict__ Wg,
                                          const float* __restrict__ bfv,
                                          const float* __restrict__ bgv,
                                          float* __restrict__ s_part) {
    __shared__ float xl[16 * 257 * 4];       // [i][c][px], dword stride 1028 per i
    __shared__ float FG[2][4 * 16 * 36];     // [fg][px*576 + i*36 + d]

    const int t   = threadIdx.x;
    const int blk = blockIdx.x;

    // FG-compute mapping
    const int i_  = t >> 5;          // batch 0..15
    const int sub = t & 31;
    const int cq  = sub & 7;         // col quad (of 32 cols -> 8 quads)
    const int fg  = (sub >> 3) & 1;  // 0: f, 1: g
    const int ph  = sub >> 4;        // pixel half (0..1)
    const float* W    = fg ? Wg : Wf;
    const float* bias = fg ? bgv : bfv;

    // s-partial mapping
    const int sp_ph = t >> 8;        // 0..1
    const int sp_i  = (t >> 4) & 15;
    const int sp_j  = t & 15;
    float sacc = 0.f;

    for (int it = 0; it < 4; ++it) {
        const int p0 = (blk * 4 + it) * 4;
        // ---- stage x[16 batches][4 px][256 c] into [i][c][px] ----
        {
            const int r  = t >> 3;         // 0..63 row = (i,px)
            const int q8 = t & 7;
            const int ii = r >> 2, px = r & 3;
            const float* src = x + (((ii << 12) + (p0 + px)) << 8);
            float* dstb = xl + ii * 1028 + px;
            #pragma unroll
            for (int cc = 0; cc < 8; ++cc) {
                const int c = q8 * 4 + cc * 32;
                f4 v = *(const f4*)(src + c);
                dstb[(c + 0) * 4] = v[0];
                dstb[(c + 1) * 4] = v[1];
                dstb[(c + 2) * 4] = v[2];
                dstb[(c + 3) * 4] = v[3];
            }
        }
        __syncthreads();
        // ---- compute f/g: acc[4 cols][2 px] ----
        float acc0[4] = {0.f, 0.f, 0.f, 0.f};
        float acc1[4] = {0.f, 0.f, 0.f, 0.f};
        {
            const float* wp = W + cq * 4;
            const float* xp = xl + i_ * 1028 + ph * 2;
            #pragma unroll 8
            for (int c = 0; c < 256; ++c) {
                f4 w4 = *(const f4*)(wp + c * 32);
                f2 xv = *(const f2*)(xp + c * 4);
                #pragma unroll
                for (int cl = 0; cl < 4; ++cl) {
                    acc0[cl] += w4[cl] * xv[0];
                    acc1[cl] += w4[cl] * xv[1];
                }
            }
        }
        // bias + write to FG lds
        {
            float* d0 = &FG[fg][(ph * 2 + 0) * 576 + i_ * 36 + cq * 4];
            float* d1 = &FG[fg][(ph * 2 + 1) * 576 + i_ * 36 + cq * 4];
            #pragma unroll
            for (int cl = 0; cl < 4; ++cl) {
                const float b = bias[cq * 4 + cl];
                d0[cl] = acc0[cl] + b;
                d1[cl] = acc1[cl] + b;
            }
        }
        __syncthreads();
        // ---- partial s: s[i][j] += sum_d g[i,d] * f[j,d] over 2 pixels ----
        #pragma unroll
        for (int pp = 0; pp < 2; ++pp) {
            const int px = sp_ph * 2 + pp;
            const float* Gp = &FG[1][px * 576 + sp_i * 36];
            const float* Fp = &FG[0][px * 576 + sp_j * 36];
            #pragma unroll 8
            for (int d = 0; d < 32; ++d) sacc += Gp[d] * Fp[d];
        }
    }
    s_part[(blk * 2 + sp_ph) * 256 + (sp_i * 16 + sp_j)] = sacc;
}

// ---------------- KB: reduce partials + softmax -> beta ----------------
__global__ __launch_bounds__(1024) void kb(const float* __restrict__ s_part,
                                           float* __restrict__ beta) {
    __shared__ float red[4 * 256];
    __shared__ float srow[256];
    __shared__ float erow[256];
    const int t = threadIdx.x;
    const int pair = t & 255;
    const int qr = t >> 8;       // 0..3
    float a = 0.f;
    for (int b = qr * 128; b < qr * 128 + 128; ++b) a += s_part[b * 256 + pair];
    red[qr * 256 + pair] = a;
    __syncthreads();
    float s = 0.f, e = 0.f;
    if (t < 256) {
        s = red[pair] + red[256 + pair] + red[512 + pair] + red[768 + pair];
        srow[pair] = s;
    }
    __syncthreads();
    if (t < 256) {
        const int i = pair >> 4;
        float m = srow[i * 16];
        #pragma unroll
        for (int j = 1; j < 16; ++j) m = fmaxf(m, srow[i * 16 + j]);
        e = __expf(s - m);
        e = expf(s - m);
        erow[pair] = e;
    }
    __syncthreads();
    if (t < 256) {
        const int i = pair >> 4;
        float sum = 0.f;
        #pragma unroll
        for (int j = 0; j < 16; ++j) sum += erow[i * 16 + j];
        beta[pair] = e / sum;
    }
}

// ---------------- KC: mix (beta @ x) + GEMM(bf16 MFMA) + residual ----------------
// grid 1024 x 256 threads (4 waves). 4 pixels/block. M=64 rows (r = i*4 + q).
__global__ __launch_bounds__(256) void kc(const float* __restrict__ x,
                                          const unsigned short* __restrict__ WhT,
                                          const float* __restrict__ gb,
                                          const float* __restrict__ beta,
                                          float* __restrict__ out) {
    __shared__ __align__(16) unsigned char smem[32 * 1024 + 1024];
    float* beta_l = (float*)(smem + 32 * 1024);

    const int t = threadIdx.x;
    const int w = t >> 6;          // wave id = pixel q
    const int l = t & 63;
    const int p0 = blockIdx.x * 4;
    const int p  = p0 + w;
    const int c4 = l;              // column quad index 0..63
    const int cbase = c4 * 4;

    beta_l[t] = beta[t];
    f4 gb4 = *(const f4*)(gb + cbase);
    __syncthreads();

    // ---- mixing: xm[r=i*4+w][cbase..cbase+3] = sum_j beta[i][j] * x[j][p][c] ----
    f4 xr[16];
    #pragma unroll
    for (int j = 0; j < 16; ++j)
        xr[j] = *(const f4*)(x + (((j << 12) + p) << 8) + cbase);
    #pragma unroll
    for (int i = 0; i < 16; ++i) {
        f4 a = {0.f, 0.f, 0.f, 0.f};
        #pragma unroll
        for (int j = 0; j < 16; ++j) a += xr[j] * beta_l[i * 16 + j];
        const int r = i * 4 + w;
        int bo = r * 512 + c4 * 8;
        bo ^= (r & 7) << 4;                      // XOR swizzle (T2)
        u32x2 packed;
        packed[0] = ((unsigned)f2bf(a[1]) << 16) | f2bf(a[0]);
        packed[1] = ((unsigned)f2bf(a[3]) << 16) | f2bf(a[2]);
        *(u32x2*)(smem + bo) = packed;
    }
    __syncthreads();

    // ---- GEMM: [64 x 256(k)] @ WhT -> wave owns 64 cols ----
    f32x4 acc[4][4];
    #pragma unroll
    for (int mt = 0; mt < 4; ++mt)
        #pragma unroll
        for (int nt = 0; nt < 4; ++nt) acc[mt][nt] = (f32x4){0.f, 0.f, 0.f, 0.f};

    const int n0 = w * 64;
    const int lrow = l & 15;
    const int kf = (l >> 4) * 8;
    #pragma unroll
    for (int k0 = 0; k0 < 256; k0 += 32) {
        short8 af[4], bf_[4];
        #pragma unroll
        for (int mt = 0; mt < 4; ++mt) {
            const int row = mt * 16 + lrow;
            int bo = row * 512 + (k0 + kf) * 2;
            bo ^= (row & 7) << 4;
            af[mt] = *(const short8*)(smem + bo);
        }
        #pragma unroll
        for (int nt = 0; nt < 4; ++nt) {
            const int d = n0 + nt * 16 + lrow;
            bf_[nt] = *(const short8*)(WhT + d * 256 + k0 + kf);
        }
        #pragma unroll
        for (int mt = 0; mt < 4; ++mt)
            #pragma unroll
            for (int nt = 0; nt < 4; ++nt)
                acc[mt][nt] = __builtin_amdgcn_mfma_f32_16x16x32_bf16(
                    af[mt], bf_[nt], acc[mt][nt], 0, 0, 0);
    }

    // ---- epilogue: stage C via LDS (2 halves), add gamma*bh + x (from regs) ----
    float* cst = (float*)smem;
    #pragma unroll
    for (int h = 0; h < 2; ++h) {
        __syncthreads();
        #pragma unroll
        for (int mt = 2 * h; mt < 2 * h + 2; ++mt)
            #pragma unroll
            for (int nt = 0; nt < 4; ++nt)
                #pragma unroll
                for (int j = 0; j < 4; ++j) {
                    const int row = mt * 16 + (l >> 4) * 4 + j - h * 32;
                    const int col = n0 + nt * 16 + lrow;
                    cst[row * 256 + col] = acc[mt][nt][j];
                }
        __syncthreads();
        #pragma unroll
        for (int rr = 0; rr < 8; ++rr) {
            const int rl = w + rr * 4;          // local row 0..31
            const int i  = h * 8 + rr;          // batch index (q == w)
            const int idx = (((i << 12) + p) << 8) + cbase;
            f4 o = *(const f4*)(cst + rl * 256 + cbase);
            o += gb4 + xr[i];
            *(f4*)(out + idx) = o;
        }
    }
}

extern "C" void kernel_launch(void* const* d_in, const int* in_sizes, int n_in,
                              void* d_out, int out_size, void* d_ws, size_t ws_size,
                              hipStream_t stream) {
    const float* x     = (const float*)d_in[0];
    const float* Wf    = (const float*)d_in[1];
    const float* Wg    = (const float*)d_in[2];
    const float* Wh    = (const float*)d_in[3];
    const float* bfv   = (const float*)d_in[4];
    const float* bgv   = (const float*)d_in[5];
    const float* bhv   = (const float*)d_in[6];
    const float* gamma = (const float*)d_in[7];
    float* out = (float*)d_out;

    char* ws = (char*)d_ws;
    unsigned short* WhT = (unsigned short*)ws;            // 131072 B
    float* gb     = (float*)(ws + 131072);                // 1024 B
    float* beta   = (float*)(ws + 132096);                // 1024 B
    float* s_part = (float*)(ws + 133120);                // 512*256*4 B

    k_setup<<<dim3(256), dim3(256), 0, stream>>>(Wh, bhv, gamma, WhT, gb);
    ka<<<dim3(256), dim3(512), 0, stream>>>(x, Wf, Wg, bfv, bgv, s_part);
    kb<<<dim3(1), dim3(1024), 0, stream>>>(s_part, beta);
    kc<<<dim3(1024), dim3(256), 0, stream>>>(x, WhT, gb, beta, out);
}